// Round 12
// baseline (587.512 us; speedup 1.0000x reference)
//
#include <hip/hip_runtime.h>
#include <math.h>

constexpr int D = 64;      // input / output feature dim
constexpr int H = 128;     // GRU hidden dim
constexpr int MAXLEN = 512;
constexpr int MSEQ = 4;    // sequences per block (4x N-col duplication)

typedef __attribute__((ext_vector_type(8))) short short8;  // 8 bf16 = 4 VGPRs
typedef __attribute__((ext_vector_type(4))) float f32x4;   // MFMA accumulator

__device__ __forceinline__ short f2bf(float f) {           // f32 -> bf16 RNE (weight packs)
    unsigned u = __float_as_uint(f);
    u += 0x7fffu + ((u >> 16) & 1u);
    return (short)(u >> 16);
}
// HW packed convert: 2 x f32 -> 2 x bf16 (RNE), single VALU instr
__device__ __forceinline__ unsigned cvtpk(float a, float b) {
    unsigned r;
    asm volatile("v_cvt_pk_bf16_f32 %0, %1, %2" : "=v"(r) : "v"(a), "v"(b));
    return r;
}
__device__ __forceinline__ short8 pack8(float4 a, float4 b) {
    short8 r;
    r[0]=f2bf(a.x); r[1]=f2bf(a.y); r[2]=f2bf(a.z); r[3]=f2bf(a.w);
    r[4]=f2bf(b.x); r[5]=f2bf(b.y); r[6]=f2bf(b.z); r[7]=f2bf(b.w);
    return r;
}
__device__ __forceinline__ float rcp_(float x) { return __builtin_amdgcn_rcpf(x); }
__device__ __forceinline__ float sig_(float v) { return rcp_(1.0f + __expf(-v)); }
__device__ __forceinline__ float tanh_(float v) {          // round-6/10 verified form
    float a = fabsf(v);
    float e = __expf(2.0f * a);
    float t = 1.0f - 2.0f * rcp_(e + 1.0f);
    return copysignf(t, v);
}
// lgkm-only barrier: orders LDS producer->consumer without draining vmcnt;
// global x prefetches stay in flight across the barrier (T4 pattern).
__device__ __forceinline__ void lgkm_barrier() {
    asm volatile("s_waitcnt lgkmcnt(0)\n\ts_barrier" ::: "memory");
}
// static 4-way select (cndmask chain; rule-#20-safe, no runtime indexing)
__device__ __forceinline__ float sel4(f32x4 c, bool b0, bool b1) {
    float a = b0 ? c[1] : c[0];
    float b = b0 ? c[3] : c[2];
    return b1 ? b : a;
}

#define MFMA(a,b,c) __builtin_amdgcn_mfma_f32_16x16x32_bf16((a),(b),(c),0,0,0)

// 512 threads = 8 waves. MSEQ=4 -> grid 512 = TWO INDEPENDENT BLOCKS PER CU
// (separate barrier domains de-phase and fill each other's latency bubbles).
// __launch_bounds__(512,2): VGPR cap 128 (empirically calibrated: arg=4 caps
// at 64 and SPILLED in round 11 -> 76MB scratch writes). VGPR ~100 < 128 ->
// 16 waves/CU hardware occupancy = 2 co-resident blocks, NO spill.
// Swapped operands: gates^T[384,16] = W[384,K].state^T[K,16]; N-cols s, s+4,
// s+8, s+12 duplicate seq sq=s&3 -> h ds_reads are 4-way broadcast and each
// lane finishes exactly ONE feature (j2 = s>>2): 6 transcendentals/lane/step.
__global__ __launch_bounds__(512, 2)
void gru_m4(const float* __restrict__ x,
            const int* __restrict__ offsets,   // int32 (JAX x64 disabled)
            const float* __restrict__ W_ih,
            const float* __restrict__ W_hh,
            const float* __restrict__ W_dense,
            const float* __restrict__ b_dense,
            float* __restrict__ out,
            int B, int T)
{
    const int bb  = blockIdx.x;
    const int tid = threadIdx.x;      // 0..511
    const int w   = tid >> 6;         // wave 0..7
    const int l   = tid & 63;
    const int s   = l & 15;           // MFMA m/n index
    const int q   = l >> 4;           // k-group 0..3
    const int sq  = s & 3;            // sequence within block (4x dup)
    const int j2  = s >> 2;           // 0..3: which C row (feature) this lane owns
    const bool jb0 = (j2 & 1) != 0, jb1 = (j2 & 2) != 0;

    __shared__ __align__(16) short h_bf[2][MSEQ * H];   // 2 x 1KB, row 256B, XOR-swizzled
    __shared__ __align__(16) short x_bf[2][MSEQ * D];   // 2 x 512B, row 128B, XOR-swizzled
    __shared__ int slen[MSEQ], sstart[MSEQ];
    __shared__ float h_f32[MSEQ][H];

    // ---- sequence bounds ----
    if (tid < MSEQ) {
        int sg = bb * MSEQ + tid;
        int st = 0, en = 1;
        if (sg < B) { st = offsets[sg]; en = (sg + 1 < B) ? offsets[sg + 1] : T; }
        int ln = en - st;
        ln = max(1, min(ln, MAXLEN));
        sstart[tid] = st; slen[tid] = ln;
    }
    if (tid < 256) ((int*)h_bf[0])[tid] = 0;   // zero h buffer 0 (256 dwords)
    __syncthreads();

    int nt = 1;
#pragma unroll
    for (int i = 0; i < MSEQ; ++i) nt = max(nt, slen[i]);

    // ---- A-frags: weight rows in registers (one-time). Row = g*H + w*16 + s ----
    short8 Wh[3][4];   // [gate][kt], K=128
    short8 Wi[3][2];   // [gate][kt], K=64
#pragma unroll
    for (int g = 0; g < 3; ++g) {
        const int grow = g * H + w * 16 + s;
        const float* ph = W_hh + (size_t)grow * H + q * 8;
#pragma unroll
        for (int kt = 0; kt < 4; ++kt)
            Wh[g][kt] = pack8(*(const float4*)(ph + kt * 32),
                              *(const float4*)(ph + kt * 32 + 4));
        const float* pi = W_ih + (size_t)grow * D + q * 8;
#pragma unroll
        for (int kt = 0; kt < 2; ++kt)
            Wi[g][kt] = pack8(*(const float4*)(pi + kt * 32),
                              *(const float4*)(pi + kt * 32 + 4));
    }

    // ---- per-lane LDS byte offsets (16B-chunk XOR swizzle keyed by row sq) ----
    int hoff[4], xoff[2];
#pragma unroll
    for (int kt = 0; kt < 4; ++kt) hoff[kt] = sq * 256 + (((kt * 4 + q) ^ sq) << 4);
#pragma unroll
    for (int kt = 0; kt < 2; ++kt) xoff[kt] = sq * 128 + (((kt * 4 + q) ^ sq) << 4);
    // h write: ONE bf16 at feature f0 = w*16 + q*4 + j2, row sq.
    const int woff = sq * 256 + ((((2 * w) + (q >> 1)) ^ sq) << 4)
                   + ((q & 1) << 3) + (j2 << 1);

    // ---- x staging: row = w&3, halves split by w>>2; lanes l<16 (balanced) ----
    const bool xact = (l < 16);
    const int  xrow = w & 3;
    const int  pxx  = ((w >> 2) << 4) + l;      // float2 index 0..31 within row
    const int  st_x = sstart[xrow];
    const int  ln_x = slen[xrow];
    const float* xg = x + (size_t)st_x * D + pxx * 2;
    const int xwoff = xrow * 128 + (((pxx >> 2) ^ xrow) << 4) + ((pxx & 3) << 2);

    if (xact) {   // stage x row 0 into buf 0
        float2 v = *(const float2*)xg;
        *(unsigned*)((char*)x_bf[0] + xwoff) = cvtpk(v.x, v.y);
    }
    float2 xpf = {0.f, 0.f};
    if (xact) xpf = *(const float2*)(xg + (size_t)min(1, ln_x - 1) * D);

    const int ln_s = slen[sq];
    float h0 = 0.f;                   // fp32 master state: ONE feature/lane

    __syncthreads();                  // x_bf[0], h_bf[0] visible

    for (int t = 0; t < nt; ++t) {
        const int p = t & 1;
        const char* hb = (const char*)h_bf[p];
        const char* xb = (const char*)x_bf[p];

        short8 bh[4], bx[2];
#pragma unroll
        for (int kt = 0; kt < 4; ++kt) bh[kt] = *(const short8*)(hb + hoff[kt]);
#pragma unroll
        for (int kt = 0; kt < 2; ++kt) bx[kt] = *(const short8*)(xb + xoff[kt]);

        // issue x(t+2) prefetch (consumed next step's staging; never drained)
        float2 xnew = {0.f, 0.f};
        if (xact) {
            const int tn = (t + 2 < ln_x) ? t + 2 : ln_x - 1;
            xnew = *(const float2*)(xg + (size_t)tn * D);
        }

        // 18 MFMAs: gates^T = W . state^T  (4 independent chains)
        __builtin_amdgcn_s_setprio(1);
        f32x4 cr = {0,0,0,0}, cz = {0,0,0,0}, ci = {0,0,0,0}, chh = {0,0,0,0};
#pragma unroll
        for (int kt = 0; kt < 2; ++kt) {
            cr = MFMA(Wi[0][kt], bx[kt], cr);
            cz = MFMA(Wi[1][kt], bx[kt], cz);
            ci = MFMA(Wi[2][kt], bx[kt], ci);
        }
#pragma unroll
        for (int kt = 0; kt < 4; ++kt) {
            cr  = MFMA(Wh[0][kt], bh[kt], cr);
            cz  = MFMA(Wh[1][kt], bh[kt], cz);
            chh = MFMA(Wh[2][kt], bh[kt], chh);
        }
        __builtin_amdgcn_s_setprio(0);

        // gate math on this lane's ONE feature (static cndmask select)
        {
            float vr = sel4(cr, jb0, jb1);
            float vz = sel4(cz, jb0, jb1);
            float vi = sel4(ci, jb0, jb1);
            float vh = sel4(chh, jb0, jb1);
            float r  = sig_(vr);
            float z  = sig_(vz);
            float n  = tanh_(vi + r * vh);
            float hn = (1.0f - z) * n + z * h0;
            h0 = (t < ln_s) ? hn : h0;
        }

        // publish h' (one b16) + stage x(t+1) into buffer p^1
        {
            unsigned hu = cvtpk(h0, h0);
            *(short*)((char*)h_bf[p ^ 1] + woff) = (short)hu;
        }
        if (xact)
            *(unsigned*)((char*)x_bf[p ^ 1] + xwoff) = cvtpk(xpf.x, xpf.y);
        xpf = xnew;       // rotate prefetch register

        lgkm_barrier();   // LDS-only drain; x prefetch stays in flight
    }

    // ---- epilogue: h -> LDS fp32 (lane owns one feature) ----
    h_f32[sq][w * 16 + q * 4 + j2] = h0;
    __syncthreads();

    // dense(128->64) + L2 normalize: 4 seqs x 64 cols = threads 0..255
    if (tid < 256) {
        const int s2 = tid >> 6;      // seq 0..3
        const int cb = tid & 63;      // col 0..63
        float acc = b_dense[cb];
        const float* wd = W_dense + (size_t)cb * H;
        float a0=0.f,a1=0.f,a2=0.f,a3=0.f;
#pragma unroll
        for (int j = 0; j < H; j += 4) {
            float4 hv = *(const float4*)&h_f32[s2][j];   // wave-uniform broadcast
            float4 wv = *(const float4*)(wd + j);
            a0 += hv.x*wv.x; a1 += hv.y*wv.y; a2 += hv.z*wv.z; a3 += hv.w*wv.w;
        }
        acc += (a0 + a1) + (a2 + a3);
        float s2q = acc * acc;
#pragma unroll
        for (int off = 32; off >= 1; off >>= 1) s2q += __shfl_xor(s2q, off);
        float invn = 1.0f / fmaxf(sqrtf(s2q), 1e-12f);
        int sg = bb * MSEQ + s2;
        if (sg < B) out[(size_t)sg * D + cb] = acc * invn;
    }
}

extern "C" void kernel_launch(void* const* d_in, const int* in_sizes, int n_in,
                              void* d_out, int out_size, void* d_ws, size_t ws_size,
                              hipStream_t stream) {
    const float* x       = (const float*)d_in[0];
    const int*   offsets = (const int*)d_in[1];
    const float* W_ih    = (const float*)d_in[2];
    const float* W_hh    = (const float*)d_in[3];
    const float* W_dense = (const float*)d_in[4];
    const float* b_dense = (const float*)d_in[5];
    float*       out     = (float*)d_out;

    const int B = in_sizes[1];
    const int T = in_sizes[0] / D;
    const int grid = (B + MSEQ - 1) / MSEQ;

    gru_m4<<<grid, 512, 0, stream>>>(x, offsets, W_ih, W_hh, W_dense, b_dense, out, B, T);
}

// Round 13
// 352.633 us; speedup vs baseline: 1.6661x; 1.6661x over previous
//
#include <hip/hip_runtime.h>
#include <math.h>

constexpr int D = 64;      // input / output feature dim
constexpr int H = 128;     // GRU hidden dim
constexpr int MAXLEN = 512;
constexpr int MSEQ = 8;    // sequences per block (2x N-col duplication)

typedef __attribute__((ext_vector_type(8))) short short8;  // 8 bf16 = 4 VGPRs
typedef __attribute__((ext_vector_type(4))) float f32x4;   // MFMA accumulator

__device__ __forceinline__ short f2bf(float f) {           // f32 -> bf16 RNE (weight packs)
    unsigned u = __float_as_uint(f);
    u += 0x7fffu + ((u >> 16) & 1u);
    return (short)(u >> 16);
}
__device__ __forceinline__ unsigned cvtpk(float a, float b) {  // a -> low half (verified r10)
    unsigned r;
    asm volatile("v_cvt_pk_bf16_f32 %0, %1, %2" : "=v"(r) : "v"(a), "v"(b));
    return r;
}
__device__ __forceinline__ short8 pack8(float4 a, float4 b) {
    short8 r;
    r[0]=f2bf(a.x); r[1]=f2bf(a.y); r[2]=f2bf(a.z); r[3]=f2bf(a.w);
    r[4]=f2bf(b.x); r[5]=f2bf(b.y); r[6]=f2bf(b.z); r[7]=f2bf(b.w);
    return r;
}
__device__ __forceinline__ float rcp_(float x) { return __builtin_amdgcn_rcpf(x); }
__device__ __forceinline__ float sig_(float v) { return rcp_(1.0f + __expf(-v)); }
__device__ __forceinline__ float tanh_(float v) {          // round-6/10 verified form
    float a = fabsf(v);
    float e = __expf(2.0f * a);
    float t = 1.0f - 2.0f * rcp_(e + 1.0f);
    return copysignf(t, v);
}
// lgkm-only barrier: orders LDS producer->consumer without draining vmcnt;
// global x prefetches stay in flight across the barrier (T4 pattern).
__device__ __forceinline__ void lgkm_barrier() {
    asm volatile("s_waitcnt lgkmcnt(0)\n\ts_barrier" ::: "memory");
}

#define MFMA(a,b,c) __builtin_amdgcn_mfma_f32_16x16x32_bf16((a),(b),(c),0,0,0)

// 256 threads = 4 waves, 1 block/CU (grid 256), 1 wave/SIMD with 512-VGPR cap.
// Phase-sum model (r12 post-mortem): step = DS + MFMA + gateVALU + barrier; all
// shared-pipe throughput terms. 4 waves halves the DS phase (24 b128/step vs
// 48) at unchanged per-SIMD VALU/MFMA totals. Swapped operands:
// gates^T[384,16] = W[384,K].state^T[K,16]; wave w owns features [32w,32w+32)
// via u in {0,1} sub-tiles (round-4 verified tiling). MSEQ=8: N-cols s and s+8
// duplicate seq sq=s&7; lane finishes 2 features per u (hsel=s>>3) = 4 total.
// h: fp32 master in registers; bf16 XOR-swizzled double-buffered LDS between
// steps. One lgkm-only barrier per step; x 2-step global prefetch never drained.
__global__ __launch_bounds__(256, 1)
void gru_w4(const float* __restrict__ x,
            const int* __restrict__ offsets,   // int32 (JAX x64 disabled)
            const float* __restrict__ W_ih,
            const float* __restrict__ W_hh,
            const float* __restrict__ W_dense,
            const float* __restrict__ b_dense,
            float* __restrict__ out,
            int B, int T)
{
    const int bb   = blockIdx.x;
    const int tid  = threadIdx.x;     // 0..255
    const int w    = tid >> 6;        // wave 0..3
    const int l    = tid & 63;
    const int s    = l & 15;          // MFMA m/n index
    const int q    = l >> 4;          // k-group 0..3
    const int sq   = s & 7;           // sequence within block
    const int hsel = s >> 3;          // 0/1: which feature pair per u this lane owns

    __shared__ __align__(16) short h_bf[2][MSEQ * H];   // 2 x 2KB, row 256B, XOR-swizzled
    __shared__ __align__(16) short x_bf[2][MSEQ * D];   // 2 x 1KB, row 128B, XOR-swizzled
    __shared__ int slen[MSEQ], sstart[MSEQ];
    __shared__ float h_f32[MSEQ][H];

    // ---- sequence bounds ----
    if (tid < MSEQ) {
        int sg = bb * MSEQ + tid;
        int st = 0, en = 1;
        if (sg < B) { st = offsets[sg]; en = (sg + 1 < B) ? offsets[sg + 1] : T; }
        int ln = en - st;
        ln = max(1, min(ln, MAXLEN));
        sstart[tid] = st; slen[tid] = ln;
    }
    {   // zero h buffer 0 (512 dwords, 256 threads x 2)
        int* hz = (int*)h_bf[0];
        hz[tid] = 0; hz[tid + 256] = 0;
    }
    __syncthreads();

    int nt = 1;
#pragma unroll
    for (int i = 0; i < MSEQ; ++i) nt = max(nt, slen[i]);

    // ---- A-frags: weight rows in registers. Row = g*H + w*32 + u*16 + s ----
    short8 Wh[3][2][4];   // [gate][u][kt], K=128
    short8 Wi[3][2][2];   // [gate][u][kt], K=64
#pragma unroll
    for (int g = 0; g < 3; ++g) {
#pragma unroll
        for (int u = 0; u < 2; ++u) {
            const int grow = g * H + w * 32 + u * 16 + s;
            const float* ph = W_hh + (size_t)grow * H + q * 8;
#pragma unroll
            for (int kt = 0; kt < 4; ++kt)
                Wh[g][u][kt] = pack8(*(const float4*)(ph + kt * 32),
                                     *(const float4*)(ph + kt * 32 + 4));
            const float* pi = W_ih + (size_t)grow * D + q * 8;
#pragma unroll
            for (int kt = 0; kt < 2; ++kt)
                Wi[g][u][kt] = pack8(*(const float4*)(pi + kt * 32),
                                     *(const float4*)(pi + kt * 32 + 4));
        }
    }

    // ---- per-lane LDS byte offsets (16B-chunk XOR swizzle keyed by row sq) ----
    int hoff[4], xoff[2], woff[2];
#pragma unroll
    for (int kt = 0; kt < 4; ++kt) hoff[kt] = sq * 256 + (((kt * 4 + q) ^ sq) << 4);
#pragma unroll
    for (int kt = 0; kt < 2; ++kt) xoff[kt] = sq * 128 + (((kt * 4 + q) ^ sq) << 4);
    // h write per u: b32 (2 bf16) at feature f0 = w*32 + u*16 + q*4 + 2*hsel, row sq.
    // byte = f0*2 -> chunk = 4w + 2u + (q>>1), off-in-chunk = (q&1)*8 + hsel*4
#pragma unroll
    for (int u = 0; u < 2; ++u)
        woff[u] = sq * 256 + ((((4 * w) + (2 * u) + (q >> 1)) ^ sq) << 4)
                + ((q & 1) << 3) + (hsel << 2);

    // ---- x staging: thread -> (seq ss = tid>>5, float2 pxx = tid&31); all active ----
    const int ss  = tid >> 5;         // 0..7
    const int pxx = tid & 31;         // 0..31
    const int st_x = sstart[ss];
    const int ln_x = slen[ss];
    const float* xg = x + (size_t)st_x * D + pxx * 2;
    const int xwoff = ss * 128 + (((pxx >> 2) ^ ss) << 4) + ((pxx & 3) << 2);

    {   // stage x row 0 into buf 0
        float2 v = *(const float2*)xg;
        *(unsigned*)((char*)x_bf[0] + xwoff) = cvtpk(v.x, v.y);
    }
    float2 xpf = *(const float2*)(xg + (size_t)min(1, ln_x - 1) * D);

    const int ln_s = slen[sq];
    float h00 = 0.f, h01 = 0.f;       // u=0 features (fp32 master)
    float h10 = 0.f, h11 = 0.f;       // u=1 features

    __syncthreads();                  // x_bf[0], h_bf[0] visible

    for (int t = 0; t < nt; ++t) {
        const int p = t & 1;
        const char* hb = (const char*)h_bf[p];
        const char* xb = (const char*)x_bf[p];

        short8 bh[4], bx[2];
#pragma unroll
        for (int kt = 0; kt < 4; ++kt) bh[kt] = *(const short8*)(hb + hoff[kt]);
#pragma unroll
        for (int kt = 0; kt < 2; ++kt) bx[kt] = *(const short8*)(xb + xoff[kt]);

        // issue x(t+2) prefetch (consumed next step's staging; never drained)
        float2 xnew;
        {
            const int tn = (t + 2 < ln_x) ? t + 2 : ln_x - 1;
            xnew = *(const float2*)(xg + (size_t)tn * D);
        }

        // 36 MFMAs: gates^T = W . state^T  (8 independent chains)
        f32x4 cr[2] = {{0,0,0,0},{0,0,0,0}};
        f32x4 cz[2] = {{0,0,0,0},{0,0,0,0}};
        f32x4 ci[2] = {{0,0,0,0},{0,0,0,0}};
        f32x4 chh[2]= {{0,0,0,0},{0,0,0,0}};
#pragma unroll
        for (int u = 0; u < 2; ++u) {
#pragma unroll
            for (int kt = 0; kt < 2; ++kt) {
                cr[u] = MFMA(Wi[0][u][kt], bx[kt], cr[u]);
                cz[u] = MFMA(Wi[1][u][kt], bx[kt], cz[u]);
                ci[u] = MFMA(Wi[2][u][kt], bx[kt], ci[u]);
            }
#pragma unroll
            for (int kt = 0; kt < 4; ++kt) {
                cr[u]  = MFMA(Wh[0][u][kt], bh[kt], cr[u]);
                cz[u]  = MFMA(Wh[1][u][kt], bh[kt], cz[u]);
                chh[u] = MFMA(Wh[2][u][kt], bh[kt], chh[u]);
            }
        }

        // gate math: 2 features per u (hsel cndmask select, no branch)
        const bool upd = (t < ln_s);
        {
            float vr0 = hsel ? cr[0][2]  : cr[0][0],  vr1 = hsel ? cr[0][3]  : cr[0][1];
            float vz0 = hsel ? cz[0][2]  : cz[0][0],  vz1 = hsel ? cz[0][3]  : cz[0][1];
            float vi0 = hsel ? ci[0][2]  : ci[0][0],  vi1 = hsel ? ci[0][3]  : ci[0][1];
            float vh0 = hsel ? chh[0][2] : chh[0][0], vh1 = hsel ? chh[0][3] : chh[0][1];
            float r0 = sig_(vr0), r1 = sig_(vr1);
            float z0 = sig_(vz0), z1 = sig_(vz1);
            float n0 = tanh_(vi0 + r0 * vh0);
            float n1 = tanh_(vi1 + r1 * vh1);
            float a0 = (1.0f - z0) * n0 + z0 * h00;
            float a1 = (1.0f - z1) * n1 + z1 * h01;
            h00 = upd ? a0 : h00;
            h01 = upd ? a1 : h01;
        }
        {
            float vr0 = hsel ? cr[1][2]  : cr[1][0],  vr1 = hsel ? cr[1][3]  : cr[1][1];
            float vz0 = hsel ? cz[1][2]  : cz[1][0],  vz1 = hsel ? cz[1][3]  : cz[1][1];
            float vi0 = hsel ? ci[1][2]  : ci[1][0],  vi1 = hsel ? ci[1][3]  : ci[1][1];
            float vh0 = hsel ? chh[1][2] : chh[1][0], vh1 = hsel ? chh[1][3] : chh[1][1];
            float r0 = sig_(vr0), r1 = sig_(vr1);
            float z0 = sig_(vz0), z1 = sig_(vz1);
            float n0 = tanh_(vi0 + r0 * vh0);
            float n1 = tanh_(vi1 + r1 * vh1);
            float a0 = (1.0f - z0) * n0 + z0 * h10;
            float a1 = (1.0f - z1) * n1 + z1 * h11;
            h10 = upd ? a0 : h10;
            h11 = upd ? a1 : h11;
        }

        // publish h' (two b32) + stage x(t+1) into buffer p^1
        *(unsigned*)((char*)h_bf[p ^ 1] + woff[0]) = cvtpk(h00, h01);
        *(unsigned*)((char*)h_bf[p ^ 1] + woff[1]) = cvtpk(h10, h11);
        *(unsigned*)((char*)x_bf[p ^ 1] + xwoff)   = cvtpk(xpf.x, xpf.y);
        xpf = xnew;       // rotate prefetch register

        lgkm_barrier();   // LDS-only drain; x prefetch stays in flight
    }

    // ---- epilogue: h -> LDS fp32 (lane owns 2 contiguous features per u) ----
    {
        float2 hv0 = { h00, h01 };
        float2 hv1 = { h10, h11 };
        *(float2*)&h_f32[sq][w * 32 + 0  + q * 4 + 2 * hsel] = hv0;
        *(float2*)&h_f32[sq][w * 32 + 16 + q * 4 + 2 * hsel] = hv1;
    }
    __syncthreads();

    // dense(128->64) + L2 normalize: 32 threads per seq, 2 cols each
    {
        const int s2 = tid >> 5;      // seq 0..7
        const int cb = tid & 31;      // col base (cols cb, cb+32)
        float acc0 = b_dense[cb];
        float acc1 = b_dense[cb + 32];
        const float* w0 = W_dense + (size_t)cb * H;
        const float* w1 = W_dense + (size_t)(cb + 32) * H;
#pragma unroll
        for (int j = 0; j < H; j += 4) {
            float4 hv = *(const float4*)&h_f32[s2][j];   // wave-uniform broadcast
            float4 a0 = *(const float4*)(w0 + j);
            float4 a1 = *(const float4*)(w1 + j);
            acc0 += hv.x*a0.x + hv.y*a0.y + hv.z*a0.z + hv.w*a0.w;
            acc1 += hv.x*a1.x + hv.y*a1.y + hv.z*a1.z + hv.w*a1.w;
        }
        float s2q = acc0 * acc0 + acc1 * acc1;
#pragma unroll
        for (int off = 16; off >= 1; off >>= 1) s2q += __shfl_xor(s2q, off);
        float invn = 1.0f / fmaxf(sqrtf(s2q), 1e-12f);
        int sg = bb * MSEQ + s2;
        if (sg < B) {
            out[(size_t)sg * D + cb]      = acc0 * invn;
            out[(size_t)sg * D + cb + 32] = acc1 * invn;
        }
    }
}

extern "C" void kernel_launch(void* const* d_in, const int* in_sizes, int n_in,
                              void* d_out, int out_size, void* d_ws, size_t ws_size,
                              hipStream_t stream) {
    const float* x       = (const float*)d_in[0];
    const int*   offsets = (const int*)d_in[1];
    const float* W_ih    = (const float*)d_in[2];
    const float* W_hh    = (const float*)d_in[3];
    const float* W_dense = (const float*)d_in[4];
    const float* b_dense = (const float*)d_in[5];
    float*       out     = (float*)d_out;

    const int B = in_sizes[1];
    const int T = in_sizes[0] / D;
    const int grid = (B + MSEQ - 1) / MSEQ;

    gru_w4<<<grid, 256, 0, stream>>>(x, offsets, W_ih, W_hh, W_dense, b_dense, out, B, T);
}

// Round 14
// 341.616 us; speedup vs baseline: 1.7198x; 1.0323x over previous
//
#include <hip/hip_runtime.h>
#include <math.h>

constexpr int D = 64;      // input / output feature dim
constexpr int H = 128;     // GRU hidden dim
constexpr int MAXLEN = 512;
constexpr int MSEQ = 8;    // sequences per block (2x N-col duplication)

typedef __attribute__((ext_vector_type(8))) short short8;  // 8 bf16 = 4 VGPRs
typedef __attribute__((ext_vector_type(4))) float f32x4;   // MFMA accumulator

__device__ __forceinline__ short f2bf(float f) {           // f32 -> bf16 RNE (weight packs)
    unsigned u = __float_as_uint(f);
    u += 0x7fffu + ((u >> 16) & 1u);
    return (short)(u >> 16);
}
__device__ __forceinline__ unsigned cvtpk(float a, float b) {  // a -> low half
    unsigned r;
    asm volatile("v_cvt_pk_bf16_f32 %0, %1, %2" : "=v"(r) : "v"(a), "v"(b));
    return r;
}
__device__ __forceinline__ short8 pack8(float4 a, float4 b) {
    short8 r;
    r[0]=f2bf(a.x); r[1]=f2bf(a.y); r[2]=f2bf(a.z); r[3]=f2bf(a.w);
    r[4]=f2bf(b.x); r[5]=f2bf(b.y); r[6]=f2bf(b.z); r[7]=f2bf(b.w);
    return r;
}
__device__ __forceinline__ float rcp_(float x) { return __builtin_amdgcn_rcpf(x); }
__device__ __forceinline__ float sig_(float v) { return rcp_(1.0f + __expf(-v)); }
__device__ __forceinline__ float tanh_(float v) {          // verified form (r6/r10/r13)
    float a = fabsf(v);
    float e = __expf(2.0f * a);
    float t = 1.0f - 2.0f * rcp_(e + 1.0f);
    return copysignf(t, v);
}
// lgkm-only barrier: orders LDS producer->consumer without draining vmcnt.
__device__ __forceinline__ void lgkm_barrier() {
    asm volatile("s_waitcnt lgkmcnt(0)\n\ts_barrier" ::: "memory");
}

#define MFMA(a,b,c) __builtin_amdgcn_mfma_f32_16x16x32_bf16((a),(b),(c),0,0,0)

// 256 threads = 4 waves, 1 block/CU (grid 256). r13 structure + IN-KERNEL gi
// PIPELINING: gi_{t+1} = x_{t+1}.W_ih^T is h-independent, so its 12 Wi-MFMAs
// are issued AFTER step t's gate math (they execute while waves wait at the
// barrier) and the accumulators (gr/gz/gn) carry across the barrier. Step t's
// critical chain: read bh -> 4-deep Wh-MFMA chains (accumulating INTO the
// carried gi accs) -> gate -> h write -> barrier. x rotation: step t reads
// x_{t+1} from buf[p^1], writes x_{t+2} into buf[p] (last read of buf[p] was
// step t-1, fenced by the barrier). Math order (gi then gh) identical to r13.
__global__ __launch_bounds__(256, 1)
void gru_p4(const float* __restrict__ x,
            const int* __restrict__ offsets,   // int32 (JAX x64 disabled)
            const float* __restrict__ W_ih,
            const float* __restrict__ W_hh,
            const float* __restrict__ W_dense,
            const float* __restrict__ b_dense,
            float* __restrict__ out,
            int B, int T)
{
    const int bb   = blockIdx.x;
    const int tid  = threadIdx.x;     // 0..255
    const int w    = tid >> 6;        // wave 0..3
    const int l    = tid & 63;
    const int s    = l & 15;          // MFMA m/n index
    const int q    = l >> 4;          // k-group 0..3
    const int sq   = s & 7;           // sequence within block
    const int hsel = s >> 3;          // 0/1: which feature pair per u this lane owns

    __shared__ __align__(16) short h_bf[2][MSEQ * H];   // 2 x 2KB, row 256B, XOR-swizzled
    __shared__ __align__(16) short x_bf[2][MSEQ * D];   // 2 x 1KB, row 128B, XOR-swizzled
    __shared__ int slen[MSEQ], sstart[MSEQ];
    __shared__ float h_f32[MSEQ][H];

    // ---- sequence bounds ----
    if (tid < MSEQ) {
        int sg = bb * MSEQ + tid;
        int st = 0, en = 1;
        if (sg < B) { st = offsets[sg]; en = (sg + 1 < B) ? offsets[sg + 1] : T; }
        int ln = en - st;
        ln = max(1, min(ln, MAXLEN));
        sstart[tid] = st; slen[tid] = ln;
    }
    {   // zero h buffer 0 (512 dwords, 256 threads x 2)
        int* hz = (int*)h_bf[0];
        hz[tid] = 0; hz[tid + 256] = 0;
    }
    __syncthreads();

    int nt = 1;
#pragma unroll
    for (int i = 0; i < MSEQ; ++i) nt = max(nt, slen[i]);

    // ---- A-frags: weight rows in registers. Row = g*H + w*32 + u*16 + s ----
    short8 Wh[3][2][4];   // [gate][u][kt], K=128
    short8 Wi[3][2][2];   // [gate][u][kt], K=64
#pragma unroll
    for (int g = 0; g < 3; ++g) {
#pragma unroll
        for (int u = 0; u < 2; ++u) {
            const int grow = g * H + w * 32 + u * 16 + s;
            const float* ph = W_hh + (size_t)grow * H + q * 8;
#pragma unroll
            for (int kt = 0; kt < 4; ++kt)
                Wh[g][u][kt] = pack8(*(const float4*)(ph + kt * 32),
                                     *(const float4*)(ph + kt * 32 + 4));
            const float* pi = W_ih + (size_t)grow * D + q * 8;
#pragma unroll
            for (int kt = 0; kt < 2; ++kt)
                Wi[g][u][kt] = pack8(*(const float4*)(pi + kt * 32),
                                     *(const float4*)(pi + kt * 32 + 4));
        }
    }

    // ---- per-lane LDS byte offsets (16B-chunk XOR swizzle keyed by row sq) ----
    int hoff[4], xoff[2], woff[2];
#pragma unroll
    for (int kt = 0; kt < 4; ++kt) hoff[kt] = sq * 256 + (((kt * 4 + q) ^ sq) << 4);
#pragma unroll
    for (int kt = 0; kt < 2; ++kt) xoff[kt] = sq * 128 + (((kt * 4 + q) ^ sq) << 4);
#pragma unroll
    for (int u = 0; u < 2; ++u)
        woff[u] = sq * 256 + ((((4 * w) + (2 * u) + (q >> 1)) ^ sq) << 4)
                + ((q & 1) << 3) + (hsel << 2);

    // ---- x staging: thread -> (seq ss = tid>>5, float2 pxx = tid&31) ----
    const int ss  = tid >> 5;         // 0..7
    const int pxx = tid & 31;         // 0..31
    const int st_x = sstart[ss];
    const int ln_x = slen[ss];
    const float* xg = x + (size_t)st_x * D + pxx * 2;
    const int xwoff = ss * 128 + (((pxx >> 2) ^ ss) << 4) + ((pxx & 3) << 2);

    {   // prologue staging: x0 -> buf0, x1 -> buf1
        float2 v0 = *(const float2*)xg;
        float2 v1 = *(const float2*)(xg + (size_t)min(1, ln_x - 1) * D);
        *(unsigned*)((char*)x_bf[0] + xwoff) = cvtpk(v0.x, v0.y);
        *(unsigned*)((char*)x_bf[1] + xwoff) = cvtpk(v1.x, v1.y);
    }
    float2 xpf = *(const float2*)(xg + (size_t)min(2, ln_x - 1) * D);  // x2

    const int ln_s = slen[sq];
    float h00 = 0.f, h01 = 0.f;       // u=0 features (fp32 master)
    float h10 = 0.f, h11 = 0.f;       // u=1 features

    __syncthreads();                  // x_bf[0/1], h_bf[0] visible

    // ---- prologue gi_0: read x0 frags, 12 Wi MFMAs -> carried accumulators ----
    const f32x4 zf = {0.f, 0.f, 0.f, 0.f};
    f32x4 gr[2], gz[2], gn[2];
    {
        short8 bx0[2];
#pragma unroll
        for (int kt = 0; kt < 2; ++kt)
            bx0[kt] = *(const short8*)((const char*)x_bf[0] + xoff[kt]);
#pragma unroll
        for (int u = 0; u < 2; ++u) {
            gr[u] = MFMA(Wi[0][u][0], bx0[0], zf);
            gr[u] = MFMA(Wi[0][u][1], bx0[1], gr[u]);
            gz[u] = MFMA(Wi[1][u][0], bx0[0], zf);
            gz[u] = MFMA(Wi[1][u][1], bx0[1], gz[u]);
            gn[u] = MFMA(Wi[2][u][0], bx0[0], zf);
            gn[u] = MFMA(Wi[2][u][1], bx0[1], gn[u]);
        }
    }
    lgkm_barrier();   // prologue reads of buf0 complete before step-0 write of buf0

    for (int t = 0; t < nt; ++t) {
        const int p = t & 1;
        const char* hb = (const char*)h_bf[p];
        const char* xb = (const char*)x_bf[p ^ 1];   // holds x_{t+1}

        // critical reads first: bh, then next-x frags
        short8 bh[4], bxn[2];
#pragma unroll
        for (int kt = 0; kt < 4; ++kt) bh[kt] = *(const short8*)(hb + hoff[kt]);
#pragma unroll
        for (int kt = 0; kt < 2; ++kt) bxn[kt] = *(const short8*)(xb + xoff[kt]);

        // 24 Wh MFMAs: 4-deep chains accumulating INTO the carried gi accs.
        // n-gate's hidden part must stay separate (n = tanh(gi_n + r*gh_n)).
        f32x4 chn[2];
#pragma unroll
        for (int u = 0; u < 2; ++u) {
            chn[u] = MFMA(Wh[2][u][0], bh[0], zf);
#pragma unroll
            for (int kt = 1; kt < 4; ++kt) chn[u] = MFMA(Wh[2][u][kt], bh[kt], chn[u]);
#pragma unroll
            for (int kt = 0; kt < 4; ++kt) {
                gr[u] = MFMA(Wh[0][u][kt], bh[kt], gr[u]);
                gz[u] = MFMA(Wh[1][u][kt], bh[kt], gz[u]);
            }
        }

        // gate math: 2 features per u (hsel cndmask select, no branch)
        const bool upd = (t < ln_s);
        {
            float vr0 = hsel ? gr[0][2] : gr[0][0], vr1 = hsel ? gr[0][3] : gr[0][1];
            float vz0 = hsel ? gz[0][2] : gz[0][0], vz1 = hsel ? gz[0][3] : gz[0][1];
            float vi0 = hsel ? gn[0][2] : gn[0][0], vi1 = hsel ? gn[0][3] : gn[0][1];
            float vh0 = hsel ? chn[0][2] : chn[0][0], vh1 = hsel ? chn[0][3] : chn[0][1];
            float r0 = sig_(vr0), r1 = sig_(vr1);
            float z0 = sig_(vz0), z1 = sig_(vz1);
            float n0 = tanh_(vi0 + r0 * vh0);
            float n1 = tanh_(vi1 + r1 * vh1);
            float a0 = (1.0f - z0) * n0 + z0 * h00;
            float a1 = (1.0f - z1) * n1 + z1 * h01;
            h00 = upd ? a0 : h00;
            h01 = upd ? a1 : h01;
        }
        {
            float vr0 = hsel ? gr[1][2] : gr[1][0], vr1 = hsel ? gr[1][3] : gr[1][1];
            float vz0 = hsel ? gz[1][2] : gz[1][0], vz1 = hsel ? gz[1][3] : gz[1][1];
            float vi0 = hsel ? gn[1][2] : gn[1][0], vi1 = hsel ? gn[1][3] : gn[1][1];
            float vh0 = hsel ? chn[1][2] : chn[1][0], vh1 = hsel ? chn[1][3] : chn[1][1];
            float r0 = sig_(vr0), r1 = sig_(vr1);
            float z0 = sig_(vz0), z1 = sig_(vz1);
            float n0 = tanh_(vi0 + r0 * vh0);
            float n1 = tanh_(vi1 + r1 * vh1);
            float a0 = (1.0f - z0) * n0 + z0 * h10;
            float a1 = (1.0f - z1) * n1 + z1 * h11;
            h10 = upd ? a0 : h10;
            h11 = upd ? a1 : h11;
        }

        // publish h' immediately (critical for next step)
        *(unsigned*)((char*)h_bf[p ^ 1] + woff[0]) = cvtpk(h00, h01);
        *(unsigned*)((char*)h_bf[p ^ 1] + woff[1]) = cvtpk(h10, h11);

        // OFF-CRITICAL: gi_{t+1} (12 Wi MFMAs on x_{t+1}) -> carried accs;
        // executes in the matrix pipe while waves head to / wait at the barrier
#pragma unroll
        for (int u = 0; u < 2; ++u) {
            gr[u] = MFMA(Wi[0][u][0], bxn[0], zf);
            gr[u] = MFMA(Wi[0][u][1], bxn[1], gr[u]);
            gz[u] = MFMA(Wi[1][u][0], bxn[0], zf);
            gz[u] = MFMA(Wi[1][u][1], bxn[1], gz[u]);
            gn[u] = MFMA(Wi[2][u][0], bxn[0], zf);
            gn[u] = MFMA(Wi[2][u][1], bxn[1], gn[u]);
        }

        // OFF-CRITICAL: stage x_{t+2} into buf p (its last reads were step t-1,
        // fenced by the barrier); prefetch x_{t+3} (never drained)
        *(unsigned*)((char*)x_bf[p] + xwoff) = cvtpk(xpf.x, xpf.y);
        {
            const int tn = (t + 3 < ln_x) ? t + 3 : ln_x - 1;
            xpf = *(const float2*)(xg + (size_t)tn * D);
        }

        lgkm_barrier();   // LDS-only drain; global prefetch stays in flight
    }

    // ---- epilogue: h -> LDS fp32 (lane owns 2 contiguous features per u) ----
    {
        float2 hv0 = { h00, h01 };
        float2 hv1 = { h10, h11 };
        *(float2*)&h_f32[sq][w * 32 + 0  + q * 4 + 2 * hsel] = hv0;
        *(float2*)&h_f32[sq][w * 32 + 16 + q * 4 + 2 * hsel] = hv1;
    }
    __syncthreads();

    // dense(128->64) + L2 normalize: 32 threads per seq, 2 cols each
    {
        const int s2 = tid >> 5;      // seq 0..7
        const int cb = tid & 31;      // col base (cols cb, cb+32)
        float acc0 = b_dense[cb];
        float acc1 = b_dense[cb + 32];
        const float* w0 = W_dense + (size_t)cb * H;
        const float* w1 = W_dense + (size_t)(cb + 32) * H;
#pragma unroll
        for (int j = 0; j < H; j += 4) {
            float4 hv = *(const float4*)&h_f32[s2][j];   // wave-uniform broadcast
            float4 a0 = *(const float4*)(w0 + j);
            float4 a1 = *(const float4*)(w1 + j);
            acc0 += hv.x*a0.x + hv.y*a0.y + hv.z*a0.z + hv.w*a0.w;
            acc1 += hv.x*a1.x + hv.y*a1.y + hv.z*a1.z + hv.w*a1.w;
        }
        float s2q = acc0 * acc0 + acc1 * acc1;
#pragma unroll
        for (int off = 16; off >= 1; off >>= 1) s2q += __shfl_xor(s2q, off);
        float invn = 1.0f / fmaxf(sqrtf(s2q), 1e-12f);
        int sg = bb * MSEQ + s2;
        if (sg < B) {
            out[(size_t)sg * D + cb]      = acc0 * invn;
            out[(size_t)sg * D + cb + 32] = acc1 * invn;
        }
    }
}

extern "C" void kernel_launch(void* const* d_in, const int* in_sizes, int n_in,
                              void* d_out, int out_size, void* d_ws, size_t ws_size,
                              hipStream_t stream) {
    const float* x       = (const float*)d_in[0];
    const int*   offsets = (const int*)d_in[1];
    const float* W_ih    = (const float*)d_in[2];
    const float* W_hh    = (const float*)d_in[3];
    const float* W_dense = (const float*)d_in[4];
    const float* b_dense = (const float*)d_in[5];
    float*       out     = (float*)d_out;

    const int B = in_sizes[1];
    const int T = in_sizes[0] / D;
    const int grid = (B + MSEQ - 1) / MSEQ;

    gru_p4<<<grid, 256, 0, stream>>>(x, offsets, W_ih, W_hh, W_dense, b_dense, out, B, T);
}